// Round 1
// baseline (49.811 us; speedup 1.0000x reference)
//
#include <hip/hip_runtime.h>

// SingleShotInhibition: out[b,f,hw] = act[b,f,hw] + sum_m filt[m]*act[b,(f+m-13)&511,hw]
// act: [64, 512, 28, 28] fp32, filt: [27] fp32 (center tap == 0 in the data).
//
// Strategy: memory-bound (206 MB min traffic -> ~33us roofline). Each thread
// owns one (b,hw) position; each block computes a 32-channel output chunk by
// staging the 58-channel input window in registers (statically indexed,
// fully unrolled -> no scratch). Coalesced loads/stores across hw.

#define SSI_SCOPE 27
#define SSI_HALO  13
#define SSI_C     512
#define SSI_HW    784            // 28*28
#define SSI_CHUNK 32             // output channels per block
#define SSI_NCHNK 16             // 512 / 32
#define SSI_POSB  256            // positions per block (= threads)
// positions total: 64*784 = 50176 = 196 * 256

__global__ __launch_bounds__(256) void ssi_kernel(
    const float* __restrict__ act,
    const float* __restrict__ filt,
    float* __restrict__ out)
{
    const int bid      = blockIdx.x;
    const int pos_tile = bid >> 4;            // / SSI_NCHNK
    const int ch0      = (bid & (SSI_NCHNK - 1)) * SSI_CHUNK;

    const int p  = pos_tile * SSI_POSB + (int)threadIdx.x;  // < 50176 exactly
    const int b  = p / SSI_HW;
    const int hw = p - b * SSI_HW;

    const float* __restrict__ base  = act + (size_t)b * (SSI_C * SSI_HW) + hw;
    float* __restrict__       obase = out + (size_t)b * (SSI_C * SSI_HW) + hw;

    // 27 filter taps: uniform address -> scalar loads / SGPRs.
    float w[SSI_SCOPE];
#pragma unroll
    for (int m = 0; m < SSI_SCOPE; ++m) w[m] = filt[m];

    // Stage the 58-channel input window in registers (compile-time indices).
    float v[SSI_CHUNK + SSI_SCOPE - 1];
#pragma unroll
    for (int k = 0; k < SSI_CHUNK + SSI_SCOPE - 1; ++k) {
        const int c = (ch0 - SSI_HALO + k) & (SSI_C - 1);   // circular wrap
        v[k] = base[c * SSI_HW];
    }

    // 32 outputs x 27 taps, fully unrolled. Residual = v[j+13]; w[13]==0 so
    // including tap 13 in the sum adds nothing (and stays correct regardless).
#pragma unroll
    for (int j = 0; j < SSI_CHUNK; ++j) {
        float acc = v[j + SSI_HALO];
#pragma unroll
        for (int m = 0; m < SSI_SCOPE; ++m) {
            acc = fmaf(w[m], v[j + m], acc);
        }
        obase[(ch0 + j) * SSI_HW] = acc;
    }
}

extern "C" void kernel_launch(void* const* d_in, const int* in_sizes, int n_in,
                              void* d_out, int out_size, void* d_ws, size_t ws_size,
                              hipStream_t stream) {
    const float* act  = (const float*)d_in[0];   // 64*512*28*28 fp32
    const float* filt = (const float*)d_in[1];   // 27 fp32
    float* out = (float*)d_out;

    const int pos_tiles = (64 * SSI_HW) / SSI_POSB;  // 196
    dim3 grid(pos_tiles * SSI_NCHNK);                // 3136 blocks
    dim3 block(SSI_POSB);
    hipLaunchKernelGGL(ssi_kernel, grid, block, 0, stream, act, filt, out);
}